// Round 4
// baseline (907.135 us; speedup 1.0000x reference)
//
#include <hip/hip_runtime.h>
#include <hip/hip_bf16.h>

#define N_NODE 2000
#define BB 4
#define CC 32
#define LL 3
#define WW 10
#define M3 6000
#define MP 6016
#define KP 6016
#define NCOL 1280

typedef __bf16 bf16x8 __attribute__((ext_vector_type(8)));
typedef float f32x4 __attribute__((ext_vector_type(4)));

__device__ __forceinline__ float sigmoidf_(float x) { return 1.0f / (1.0f + __expf(-x)); }
__device__ __forceinline__ float tanhf_(float x) { return 1.0f - 2.0f / (__expf(2.0f * x) + 1.0f); }

// ---------- build padded bf16 A with temporal_adj corner blocks ----------
__global__ __launch_bounds__(256) void k_build_A(const float* __restrict__ adj,
                                                 const float* __restrict__ tadj,
                                                 __hip_bfloat16* __restrict__ A) {
  const int m = blockIdx.x * 256 + threadIdx.x;
  const int n = blockIdx.y;
  if (m >= KP) return;
  float v = 0.0f;
  if (n < M3 && m < M3) {
    const bool nr = (n < N_NODE) | (n >= 2 * N_NODE);
    const bool mr = (m < N_NODE) | (m >= 2 * N_NODE);
    if (nr & mr) {
      const int nn = (n >= 2 * N_NODE) ? n - 2 * N_NODE : n;
      const int mm = (m >= 2 * N_NODE) ? m - 2 * N_NODE : m;
      v = tadj[(size_t)nn * N_NODE + mm];
    } else {
      v = adj[(size_t)n * M3 + m];
    }
  }
  A[(size_t)n * KP + m] = __float2bfloat16(v);
}

// ---------- build H0^T [col=w*128+b*32+c][m=s*N+n] = x + embeddings ----------
__global__ __launch_bounds__(256) void k_build_H(const float* __restrict__ x,
                                                 const float* __restrict__ temb,
                                                 const float* __restrict__ semb,
                                                 __hip_bfloat16* __restrict__ H) {
  const int m = blockIdx.x * 256 + threadIdx.x;
  const int col = blockIdx.y;
  if (m >= KP) return;
  float v = 0.0f;
  if (m < M3) {
    const int w = col >> 7, b = (col >> 5) & 3, c = col & 31;
    const int s = (m >= 2 * N_NODE) ? 2 : (m >= N_NODE ? 1 : 0);
    const int n = m - s * N_NODE;
    const int tt = w + s;
    v = x[(((size_t)b * 12 + tt) * N_NODE + n) * CC + c] + temb[tt * CC + c] +
        semb[(size_t)n * CC + c];
  }
  H[(size_t)col * KP + m] = __float2bfloat16(v);
}

// ---------- 128x128 tile bf16 GEMM: G[MP][NCOL] = A[MP][KP] * Bt[NCOL][KP]^T ----------
// Conservative staging: reg-staged global loads + linear padded LDS, no swizzle.
__global__ __launch_bounds__(256) void k_gemm(const __hip_bfloat16* __restrict__ A,
                                              const __hip_bfloat16* __restrict__ Bt,
                                              float* __restrict__ G) {
  // [128 rows][72 bf16]: 144B row stride (16B-aligned); 2-way bank alias only.
  __shared__ __align__(16) __hip_bfloat16 lA[128][72];
  __shared__ __align__(16) __hip_bfloat16 lB[128][72];
  const int tid = threadIdx.x;
  const int lane = tid & 63;
  const int wv = tid >> 6;
  const int wr = wv >> 1, wc = wv & 1;
  const long row0 = (long)blockIdx.x * 128;
  const long col0 = (long)blockIdx.y * 128;

  const int srow = tid >> 3;  // 0..31
  const int scol = tid & 7;   // which 16B chunk of the 128B k-row
  const char* gA = (const char*)A;
  const char* gB = (const char*)Bt;

  const int rrow = lane & 15;
  const int koff = (lane >> 4) << 4;  // byte offset of this lane's 8-elem k-chunk

  f32x4 acc[4][4] = {};

  const int NKT = KP / 64;
  for (int kt = 0; kt < NKT; ++kt) {
    __syncthreads();
#pragma unroll
    for (int i = 0; i < 4; ++i) {
      const int r = i * 32 + srow;
      const size_t goff = (size_t)kt * 128 + (size_t)scol * 16;
      bf16x8 va = *(const bf16x8*)(gA + (size_t)(row0 + r) * (KP * 2) + goff);
      bf16x8 vb = *(const bf16x8*)(gB + (size_t)(col0 + r) * (KP * 2) + goff);
      *(bf16x8*)((char*)&lA[r][0] + scol * 16) = va;
      *(bf16x8*)((char*)&lB[r][0] + scol * 16) = vb;
    }
    __syncthreads();
#pragma unroll
    for (int ks = 0; ks < 2; ++ks) {
      bf16x8 af[4], bfr[4];
#pragma unroll
      for (int mi = 0; mi < 4; ++mi)
        af[mi] = *(const bf16x8*)((const char*)&lA[wr * 64 + mi * 16 + rrow][0] + ks * 64 + koff);
#pragma unroll
      for (int ni = 0; ni < 4; ++ni)
        bfr[ni] = *(const bf16x8*)((const char*)&lB[wc * 64 + ni * 16 + rrow][0] + ks * 64 + koff);
#pragma unroll
      for (int mi = 0; mi < 4; ++mi)
#pragma unroll
        for (int ni = 0; ni < 4; ++ni)
          acc[mi][ni] =
              __builtin_amdgcn_mfma_f32_16x16x32_bf16(af[mi], bfr[ni], acc[mi][ni], 0, 0, 0);
    }
  }
  // C/D layout (verified m89/m91): col = lane&15, row = (lane>>4)*4 + reg
  const int crow = (lane >> 4) * 4;
  const int ccol = lane & 15;
#pragma unroll
  for (int mi = 0; mi < 4; ++mi) {
#pragma unroll
    for (int ni = 0; ni < 4; ++ni) {
      const long r = row0 + wr * 64 + mi * 16 + crow;
      const long cix = col0 + wc * 64 + ni * 16 + ccol;
      float* gp = G + (size_t)r * NCOL + cix;
#pragma unroll
      for (int j = 0; j < 4; ++j) gp[(size_t)j * NCOL] = acc[mi][ni][j];
    }
  }
}

// ---------- FC (C->2C) + GLU + running max into out + next-H^T (bf16) ----------
__global__ __launch_bounds__(256) void k_fcglu(const float* __restrict__ G,
                                               const float* __restrict__ Wfc,
                                               const float* __restrict__ bfc,
                                               __hip_bfloat16* __restrict__ Hn,
                                               float* __restrict__ outb, int l, int writeH) {
  __shared__ float sW[32 * 64];
  __shared__ float sb[64];
  const int w = blockIdx.y;
  const int t = threadIdx.x;
  const float* Ws = Wfc + (size_t)(w * LL + l) * 32 * 64;
#pragma unroll
  for (int i = 0; i < 8; ++i) sW[t + 256 * i] = Ws[t + 256 * i];
  if (t < 64) sb[t] = bfc[(size_t)(w * LL + l) * 64 + t];
  __syncthreads();
  const int nl = t >> 2, b = t & 3;
  const int n = blockIdx.x * 64 + nl;
  const int colbase = w * 128 + b * 32;
  if (n >= M3) {  // zero K-padding rows of next H
    if (writeH) {
      for (int c = 0; c < 32; ++c) Hn[(size_t)(colbase + c) * KP + n] = __float2bfloat16(0.0f);
    }
    return;
  }
  const float* g = G + (size_t)n * NCOL + colbase;
  float z[64];
#pragma unroll
  for (int d = 0; d < 64; ++d) z[d] = sb[d];
  for (int c = 0; c < 32; ++c) {
    const float gv = g[c];
#pragma unroll
    for (int d = 0; d < 64; ++d) z[d] = fmaf(gv, sW[c * 64 + d], z[d]);
  }
  float h[32];
#pragma unroll
  for (int c = 0; c < 32; ++c) h[c] = z[c] * sigmoidf_(z[32 + c]);
  if (writeH) {
#pragma unroll
    for (int c = 0; c < 32; ++c) Hn[(size_t)(colbase + c) * KP + n] = __float2bfloat16(h[c]);
  }
  if (n >= N_NODE && n < 2 * N_NODE) {
    float* op = outb + (((size_t)b * WW + w) * N_NODE + (n - N_NODE)) * CC;
    if (l == 0) {
#pragma unroll
      for (int c = 0; c < 32; ++c) op[c] = h[c];
    } else {
#pragma unroll
      for (int c = 0; c < 32; ++c) op[c] = fmaxf(op[c], h[c]);
    }
  }
}

// ---------- one GRU-scan step; 32 lanes per (b,n) ----------
// Reference scan: step(hid, inp) -> (carry=yt, y=output)
//   output = u*hid + (1-u)*new_mem;  yt = sigmoid(output @ Wo + bo)
//   residual[t] = output (added to out);  NEXT hidden = yt.
__global__ __launch_bounds__(256) void k_gru(float* __restrict__ outb, float* __restrict__ state,
                                             const float* __restrict__ Wr,
                                             const float* __restrict__ brr,
                                             const float* __restrict__ Wu,
                                             const float* __restrict__ bu,
                                             const float* __restrict__ Wn,
                                             const float* __restrict__ bnn,
                                             const float* __restrict__ Wo,
                                             const float* __restrict__ bo, int w) {
  __shared__ float sI[8][32], sH[8][32], sT[8][32];
  const int t = threadIdx.x;
  const int g = t >> 5, c = t & 31;
  const int n = blockIdx.x * 8 + g;
  const int b = blockIdx.y;
  const size_t oix = (((size_t)b * WW + w) * N_NODE + n) * CC + c;
  const size_t hix = ((size_t)b * N_NODE + n) * CC + c;
  const float inp = outb[oix];
  const float hid = state[hix];
  sI[g][c] = inp;
  sH[g][c] = hid;
  __syncthreads();
  float ar = brr[c], au = bu[c];
#pragma unroll 4
  for (int d = 0; d < 32; ++d) {
    const float i_ = sI[g][d], h_ = sH[g][d];
    ar = fmaf(i_, Wr[d * 32 + c], ar);
    ar = fmaf(h_, Wr[(32 + d) * 32 + c], ar);
    au = fmaf(i_, Wu[d * 32 + c], au);
    au = fmaf(h_, Wu[(32 + d) * 32 + c], au);
  }
  const float r = sigmoidf_(ar), u = sigmoidf_(au);
  sT[g][c] = r * hid;
  __syncthreads();
  float an = bnn[c];
#pragma unroll 4
  for (int d = 0; d < 32; ++d) {
    an = fmaf(sI[g][d], Wn[d * 32 + c], an);
    an = fmaf(sT[g][d], Wn[(32 + d) * 32 + c], an);
  }
  const float nm = tanhf_(an);
  const float outv = u * hid + (1.0f - u) * nm;  // = "output" (emitted y)
  __syncthreads();
  sT[g][c] = outv;
  __syncthreads();
  float ay = bo[c];
#pragma unroll 4
  for (int d = 0; d < 32; ++d) ay = fmaf(sT[g][d], Wo[d * 32 + c], ay);
  state[hix] = sigmoidf_(ay);  // carry = yt
  outb[oix] = inp + outv;      // residual = output
}

extern "C" void kernel_launch(void* const* d_in, const int* in_sizes, int n_in, void* d_out,
                              int out_size, void* d_ws, size_t ws_size, hipStream_t stream) {
  const float* x = (const float*)d_in[0];
  const float* adj = (const float*)d_in[1];
  const float* tadj = (const float*)d_in[2];
  const float* temb = (const float*)d_in[3];
  const float* semb = (const float*)d_in[4];
  const float* Wfc = (const float*)d_in[5];
  const float* bfc = (const float*)d_in[6];
  const float* Wr = (const float*)d_in[7];
  const float* brr = (const float*)d_in[8];
  const float* Wu = (const float*)d_in[9];
  const float* bu = (const float*)d_in[10];
  const float* Wn = (const float*)d_in[11];
  const float* bnn = (const float*)d_in[12];
  const float* Wo = (const float*)d_in[13];
  const float* bo = (const float*)d_in[14];
  float* outb = (float*)d_out;

  char* ws = (char*)d_ws;
  const size_t szA = (size_t)MP * KP * 2;           // 72,384,512
  const size_t szH = (size_t)NCOL * KP * 2;         // 15,400,960
  const size_t szG = (size_t)MP * NCOL * 4;         // 30,801,920
  const size_t szS = (size_t)BB * N_NODE * CC * 4;  // 1,024,000
  if (ws_size < szA + 2 * szH + szG + szS) return;  // visible failure if ws too small

  __hip_bfloat16* A = (__hip_bfloat16*)ws;
  __hip_bfloat16* H0 = (__hip_bfloat16*)(ws + szA);
  __hip_bfloat16* H1 = (__hip_bfloat16*)(ws + szA + szH);
  float* G = (float*)(ws + szA + 2 * szH);
  float* state = (float*)(ws + szA + 2 * szH + szG);

  hipMemsetAsync(state, 0, szS, stream);
  k_build_A<<<dim3(24, KP), 256, 0, stream>>>(adj, tadj, A);
  k_build_H<<<dim3(24, NCOL), 256, 0, stream>>>(x, temb, semb, H0);

  __hip_bfloat16* Hc = H0;
  __hip_bfloat16* Hx = H1;
  for (int l = 0; l < LL; ++l) {
    k_gemm<<<dim3(47, 10), 256, 0, stream>>>(A, Hc, G);
    k_fcglu<<<dim3(94, 10), 256, 0, stream>>>(G, Wfc, bfc, Hx, outb, l, l < 2 ? 1 : 0);
    __hip_bfloat16* tmp = Hc;
    Hc = Hx;
    Hx = tmp;
  }
  for (int w = 0; w < WW; ++w)
    k_gru<<<dim3(250, BB), 256, 0, stream>>>(outb, state, Wr, brr, Wu, bu, Wn, bnn, Wo, bo, w);
}

// Round 5
// 882.184 us; speedup vs baseline: 1.0283x; 1.0283x over previous
//
#include <hip/hip_runtime.h>
#include <hip/hip_bf16.h>

#define N_NODE 2000
#define BB 4
#define CC 32
#define LL 3
#define WW 10
#define M3 6000
#define MP 6016
#define KP 6016
#define NCOL 1280

typedef __bf16 bf16x8 __attribute__((ext_vector_type(8)));
typedef float f32x4 __attribute__((ext_vector_type(4)));
typedef unsigned short ushort8 __attribute__((ext_vector_type(8)));

__device__ __forceinline__ float sigmoidf_(float x) { return 1.0f / (1.0f + __expf(-x)); }
__device__ __forceinline__ float tanhf_(float x) { return 1.0f - 2.0f / (__expf(2.0f * x) + 1.0f); }

// ---------- build padded bf16 A with temporal_adj corner blocks (8 elems/thread) ----------
__global__ __launch_bounds__(256) void k_build_A(const float* __restrict__ adj,
                                                 const float* __restrict__ tadj,
                                                 __hip_bfloat16* __restrict__ A) {
  const int m8 = blockIdx.x * 256 + threadIdx.x;  // index of 8-elem group
  const int m = m8 * 8;
  const int n = blockIdx.y;
  if (m >= KP) return;
  ushort8 out = {0, 0, 0, 0, 0, 0, 0, 0};
  if (n < M3 && m < M3) {  // region boundaries (2000/4000/6000) are 8-aligned
    const bool nr = (n < N_NODE) | (n >= 2 * N_NODE);
    const bool mr = (m < N_NODE) | (m >= 2 * N_NODE);
    const float* src;
    if (nr & mr) {
      const int nn = (n >= 2 * N_NODE) ? n - 2 * N_NODE : n;
      const int mm = (m >= 2 * N_NODE) ? m - 2 * N_NODE : m;
      src = tadj + (size_t)nn * N_NODE + mm;
    } else {
      src = adj + (size_t)n * M3 + m;
    }
#pragma unroll
    for (int j = 0; j < 8; ++j) {
      union { __hip_bfloat16 h; unsigned short u; } cv;
      cv.h = __float2bfloat16(src[j]);
      out[j] = cv.u;
    }
  }
  *(ushort8*)(A + (size_t)n * KP + m) = out;
}

// ---------- build H0^T [col=w*128+b*32+c][m=s*N+n] = x + embeddings ----------
__global__ __launch_bounds__(256) void k_build_H(const float* __restrict__ x,
                                                 const float* __restrict__ temb,
                                                 const float* __restrict__ semb,
                                                 __hip_bfloat16* __restrict__ H) {
  const int m = blockIdx.x * 256 + threadIdx.x;
  const int col = blockIdx.y;
  if (m >= KP) return;
  float v = 0.0f;
  if (m < M3) {
    const int w = col >> 7, b = (col >> 5) & 3, c = col & 31;
    const int s = (m >= 2 * N_NODE) ? 2 : (m >= N_NODE ? 1 : 0);
    const int n = m - s * N_NODE;
    const int tt = w + s;
    v = x[(((size_t)b * 12 + tt) * N_NODE + n) * CC + c] + temb[tt * CC + c] +
        semb[(size_t)n * CC + c];
  }
  H[(size_t)col * KP + m] = __float2bfloat16(v);
}

// ---------- 128x128 tile bf16 GEMM: G[MP][NCOL] = A[MP][KP] * Bt[NCOL][KP]^T ----------
// global_load_lds width-16 staging + XOR-swizzled LDS (proven equivalent to the
// conservative path in R1/R2 bit-identical experiment) + bijective XCD block remap.
__global__ __launch_bounds__(256) void k_gemm(const __hip_bfloat16* __restrict__ A,
                                              const __hip_bfloat16* __restrict__ Bt,
                                              float* __restrict__ G) {
  __shared__ __align__(16) char lA[128 * 128];  // [row][64 bf16], XOR-swizzled bytes
  __shared__ __align__(16) char lB[128 * 128];
  const int tid = threadIdx.x;
  const int lane = tid & 63;
  const int wv = tid >> 6;
  const int wr = wv >> 1, wc = wv & 1;

  // bijective XCD-chunk remap (m204): 470 blocks, 8 XCDs, q=58 r=6
  const int bid = blockIdx.x + 47 * blockIdx.y;
  const int q = 470 / 8, r = 470 % 8;
  const int xcd = bid & 7, lid = bid >> 3;
  const int swz = (xcd < r ? xcd * (q + 1) : r * (q + 1) + (xcd - r) * q) + lid;
  const int bx = swz % 47;  // row tile (fast) -> B-panel resident per XCD
  const int by = swz / 47;  // col tile
  const long row0 = (long)bx * 128;
  const long col0 = (long)by * 128;

  // staging: dest (r,chunk j) gets global chunk j ^ (r&7); r&7 == lane>>3
  const int srow = wv * 32 + (lane >> 3);
  const int soff = ((lane & 7) ^ (lane >> 3)) << 4;
  const char* gA = (const char*)A + (size_t)(row0 + srow) * (KP * 2) + soff;
  const char* gB = (const char*)Bt + (size_t)(col0 + srow) * (KP * 2) + soff;
  const size_t rstep = (size_t)8 * KP * 2;

  // reader: row rr -> chunk (k_chunk ^ (rr&7)); rr&7 == lane&7
  const int rrow = lane & 15;
  const int off0 = (((lane >> 4) << 4)) ^ ((lane & 7) << 4);
  const int off1 = (64 | ((lane >> 4) << 4)) ^ ((lane & 7) << 4);

  f32x4 acc[4][4] = {};

  const int NKT = KP / 64;
  for (int kt = 0; kt < NKT; ++kt) {
    __syncthreads();
    const char* ga = gA + (size_t)kt * 128;
    const char* gb = gB + (size_t)kt * 128;
#pragma unroll
    for (int i = 0; i < 4; ++i) {
      __builtin_amdgcn_global_load_lds(
          (const __attribute__((address_space(1))) void*)(ga + (size_t)i * rstep),
          (__attribute__((address_space(3))) void*)(lA + wv * 4096 + i * 1024), 16, 0, 0);
    }
#pragma unroll
    for (int i = 0; i < 4; ++i) {
      __builtin_amdgcn_global_load_lds(
          (const __attribute__((address_space(1))) void*)(gb + (size_t)i * rstep),
          (__attribute__((address_space(3))) void*)(lB + wv * 4096 + i * 1024), 16, 0, 0);
    }
    __syncthreads();
#pragma unroll
    for (int ks = 0; ks < 2; ++ks) {
      const int offk = ks ? off1 : off0;
      bf16x8 af[4], bfr[4];
#pragma unroll
      for (int mi = 0; mi < 4; ++mi)
        af[mi] = *(const bf16x8*)(lA + (wr * 64 + mi * 16 + rrow) * 128 + offk);
#pragma unroll
      for (int ni = 0; ni < 4; ++ni)
        bfr[ni] = *(const bf16x8*)(lB + (wc * 64 + ni * 16 + rrow) * 128 + offk);
#pragma unroll
      for (int mi = 0; mi < 4; ++mi)
#pragma unroll
        for (int ni = 0; ni < 4; ++ni)
          acc[mi][ni] =
              __builtin_amdgcn_mfma_f32_16x16x32_bf16(af[mi], bfr[ni], acc[mi][ni], 0, 0, 0);
    }
  }
  // C/D layout (verified m89/m91): col = lane&15, row = (lane>>4)*4 + reg
  const int crow = (lane >> 4) * 4;
  const int ccol = lane & 15;
#pragma unroll
  for (int mi = 0; mi < 4; ++mi) {
#pragma unroll
    for (int ni = 0; ni < 4; ++ni) {
      const long r_ = row0 + wr * 64 + mi * 16 + crow;
      const long cix = col0 + wc * 64 + ni * 16 + ccol;
      float* gp = G + (size_t)r_ * NCOL + cix;
#pragma unroll
      for (int j = 0; j < 4; ++j) gp[(size_t)j * NCOL] = acc[mi][ni][j];
    }
  }
}

// ---------- FC (C->2C) + GLU + running max into out + next-H^T (bf16) ----------
__global__ __launch_bounds__(256) void k_fcglu(const float* __restrict__ G,
                                               const float* __restrict__ Wfc,
                                               const float* __restrict__ bfc,
                                               __hip_bfloat16* __restrict__ Hn,
                                               float* __restrict__ outb, int l, int writeH) {
  __shared__ float sW[32 * 64];
  __shared__ float sb[64];
  const int w = blockIdx.y;
  const int t = threadIdx.x;
  const float* Ws = Wfc + (size_t)(w * LL + l) * 32 * 64;
#pragma unroll
  for (int i = 0; i < 8; ++i) sW[t + 256 * i] = Ws[t + 256 * i];
  if (t < 64) sb[t] = bfc[(size_t)(w * LL + l) * 64 + t];
  __syncthreads();
  const int nl = t >> 2, b = t & 3;
  const int n = blockIdx.x * 64 + nl;
  const int colbase = w * 128 + b * 32;
  if (n >= M3) {  // zero K-padding rows of next H
    if (writeH) {
      for (int c = 0; c < 32; ++c) Hn[(size_t)(colbase + c) * KP + n] = __float2bfloat16(0.0f);
    }
    return;
  }
  const float* g = G + (size_t)n * NCOL + colbase;
  float z[64];
#pragma unroll
  for (int d = 0; d < 64; ++d) z[d] = sb[d];
  for (int c = 0; c < 32; ++c) {
    const float gv = g[c];
#pragma unroll
    for (int d = 0; d < 64; ++d) z[d] = fmaf(gv, sW[c * 64 + d], z[d]);
  }
  float h[32];
#pragma unroll
  for (int c = 0; c < 32; ++c) h[c] = z[c] * sigmoidf_(z[32 + c]);
  if (writeH) {
#pragma unroll
    for (int c = 0; c < 32; ++c) Hn[(size_t)(colbase + c) * KP + n] = __float2bfloat16(h[c]);
  }
  if (n >= N_NODE && n < 2 * N_NODE) {
    float* op = outb + (((size_t)b * WW + w) * N_NODE + (n - N_NODE)) * CC;
    if (l == 0) {
#pragma unroll
      for (int c = 0; c < 32; ++c) op[c] = h[c];
    } else {
#pragma unroll
      for (int c = 0; c < 32; ++c) op[c] = fmaxf(op[c], h[c]);
    }
  }
}

// ---------- one GRU-scan step; 32 lanes per (b,n) ----------
// Reference scan: step(hid, inp) -> (carry=yt, y=output)
//   output = u*hid + (1-u)*new_mem;  yt = sigmoid(output @ Wo + bo)
//   residual[t] = output (added to out);  NEXT hidden = yt.
__global__ __launch_bounds__(256) void k_gru(float* __restrict__ outb, float* __restrict__ state,
                                             const float* __restrict__ Wr,
                                             const float* __restrict__ brr,
                                             const float* __restrict__ Wu,
                                             const float* __restrict__ bu,
                                             const float* __restrict__ Wn,
                                             const float* __restrict__ bnn,
                                             const float* __restrict__ Wo,
                                             const float* __restrict__ bo, int w) {
  __shared__ float sI[8][32], sH[8][32], sT[8][32];
  const int t = threadIdx.x;
  const int g = t >> 5, c = t & 31;
  const int n = blockIdx.x * 8 + g;
  const int b = blockIdx.y;
  const size_t oix = (((size_t)b * WW + w) * N_NODE + n) * CC + c;
  const size_t hix = ((size_t)b * N_NODE + n) * CC + c;
  const float inp = outb[oix];
  const float hid = state[hix];
  sI[g][c] = inp;
  sH[g][c] = hid;
  __syncthreads();
  float ar = brr[c], au = bu[c];
#pragma unroll 4
  for (int d = 0; d < 32; ++d) {
    const float i_ = sI[g][d], h_ = sH[g][d];
    ar = fmaf(i_, Wr[d * 32 + c], ar);
    ar = fmaf(h_, Wr[(32 + d) * 32 + c], ar);
    au = fmaf(i_, Wu[d * 32 + c], au);
    au = fmaf(h_, Wu[(32 + d) * 32 + c], au);
  }
  const float r = sigmoidf_(ar), u = sigmoidf_(au);
  sT[g][c] = r * hid;
  __syncthreads();
  float an = bnn[c];
#pragma unroll 4
  for (int d = 0; d < 32; ++d) {
    an = fmaf(sI[g][d], Wn[d * 32 + c], an);
    an = fmaf(sT[g][d], Wn[(32 + d) * 32 + c], an);
  }
  const float nm = tanhf_(an);
  const float outv = u * hid + (1.0f - u) * nm;  // = "output" (emitted y)
  __syncthreads();
  sT[g][c] = outv;
  __syncthreads();
  float ay = bo[c];
#pragma unroll 4
  for (int d = 0; d < 32; ++d) ay = fmaf(sT[g][d], Wo[d * 32 + c], ay);
  state[hix] = sigmoidf_(ay);  // carry = yt
  outb[oix] = inp + outv;      // residual = output
}

extern "C" void kernel_launch(void* const* d_in, const int* in_sizes, int n_in, void* d_out,
                              int out_size, void* d_ws, size_t ws_size, hipStream_t stream) {
  const float* x = (const float*)d_in[0];
  const float* adj = (const float*)d_in[1];
  const float* tadj = (const float*)d_in[2];
  const float* temb = (const float*)d_in[3];
  const float* semb = (const float*)d_in[4];
  const float* Wfc = (const float*)d_in[5];
  const float* bfc = (const float*)d_in[6];
  const float* Wr = (const float*)d_in[7];
  const float* brr = (const float*)d_in[8];
  const float* Wu = (const float*)d_in[9];
  const float* bu = (const float*)d_in[10];
  const float* Wn = (const float*)d_in[11];
  const float* bnn = (const float*)d_in[12];
  const float* Wo = (const float*)d_in[13];
  const float* bo = (const float*)d_in[14];
  float* outb = (float*)d_out;

  char* ws = (char*)d_ws;
  const size_t szA = (size_t)MP * KP * 2;           // 72,384,512
  const size_t szH = (size_t)NCOL * KP * 2;         // 15,400,960
  const size_t szG = (size_t)MP * NCOL * 4;         // 30,801,920
  const size_t szS = (size_t)BB * N_NODE * CC * 4;  // 1,024,000
  if (ws_size < szA + 2 * szH + szG + szS) return;  // visible failure if ws too small

  __hip_bfloat16* A = (__hip_bfloat16*)ws;
  __hip_bfloat16* H0 = (__hip_bfloat16*)(ws + szA);
  __hip_bfloat16* H1 = (__hip_bfloat16*)(ws + szA + szH);
  float* G = (float*)(ws + szA + 2 * szH);
  float* state = (float*)(ws + szA + 2 * szH + szG);

  hipMemsetAsync(state, 0, szS, stream);
  k_build_A<<<dim3(3, KP), 256, 0, stream>>>(adj, tadj, A);
  k_build_H<<<dim3(24, NCOL), 256, 0, stream>>>(x, temb, semb, H0);

  __hip_bfloat16* Hc = H0;
  __hip_bfloat16* Hx = H1;
  for (int l = 0; l < LL; ++l) {
    k_gemm<<<dim3(47, 10), 256, 0, stream>>>(A, Hc, G);
    k_fcglu<<<dim3(94, 10), 256, 0, stream>>>(G, Wfc, bfc, Hx, outb, l, l < 2 ? 1 : 0);
    __hip_bfloat16* tmp = Hc;
    Hc = Hx;
    Hx = tmp;
  }
  for (int w = 0; w < WW; ++w)
    k_gru<<<dim3(250, BB), 256, 0, stream>>>(outb, state, Wr, brr, Wu, bu, Wn, bnn, Wo, bo, w);
}